// Round 2
// baseline (289.120 us; speedup 1.0000x reference)
//
#include <hip/hip_runtime.h>
#include <math.h>

#define NB 8192
#define G 4                 // batch rows per block
#define NBLK (NB / G)
#define NNODES 32
#define TT 3
#define DIM 128
#define HID 128

// Kernel 1: uv[e][d], e<9: u[i=e/3][j=e%3][d] = W[i] row d . a_top[j]
//           e=9+t:    v[t][d]                 = W[t] row d . a_bot[t]
// Identical for all batch rows -> compute ONCE into d_ws (ws validated earlier).
__global__ __launch_bounds__(128) void gat_prep(
    const float* __restrict__ Wg,   // (3,128,128) fp32
    const float* __restrict__ ag,   // (3,256,1)   fp32
    float* __restrict__ uv)         // (12,128)    fp32
{
    int e = blockIdx.x, d = threadIdx.x;
    int wi, aoff;
    if (e < 9) { wi = e / 3; aoff = (e % 3) * 2 * HID; }        // a_top[j]
    else       { wi = e - 9; aoff = wi * 2 * HID + HID; }       // a_bot[t]
    const float* wrow = Wg + wi * DIM * HID + d * HID;
    const float* arow = ag + aoff;
    float acc = 0.f;
    #pragma unroll 16
    for (int h = 0; h < HID; ++h) acc += wrow[h] * arow[h];
    uv[e * DIM + d] = acc;
}

// data chunk (n, c) of a 32x128 fp32 row-tile lives at float4-slot n*32 + (c ^ (n&7))
// -> phase-1 column reads spread 8 lanes per 4-bank group (b128 minimum),
//    combine scalar reads stay 2-way, staging writes stay optimal.
__device__ __forceinline__ int swz_slot(int n, int c) { return n * 32 + (c ^ (n & 7)); }

// LDS-only barrier: do NOT drain vmcnt (keeps the h prefetch loads in flight,
// unlike __syncthreads(), which the compiler lowers with s_waitcnt vmcnt(0)).
__device__ __forceinline__ void lds_barrier() {
    asm volatile("s_waitcnt lgkmcnt(0)" ::: "memory");
    __builtin_amdgcn_s_barrier();
}

__global__ __launch_bounds__(256, 4) void gat_main(
    const float* __restrict__ hg,     // (B,32,128) fp32
    const int* __restrict__ maskg,    // (3,B,32) 4-byte bool words
    const float* __restrict__ Wg,     // (3,128,128) fp32
    const float* __restrict__ uv,     // (12,128) fp32 (from d_ws)
    float* __restrict__ outg)         // (B,128) fp32
{
    __shared__ __align__(16) float hL[2 * NNODES * DIM]; // 32 KB double-buffered h row (swizzled)
    __shared__ float gAll[G * TT * DIM];                 // 6 KB weighted features
    __shared__ float sTop[16];                           // [3i+j]
    __shared__ float sNb[TT * NNODES];                   // scores, overwritten in-place by weights
    __shared__ int   mvL[G * 96];                        // 1.5 KB prefetched masks
    // total 40,896 B -> 4 blocks/CU with the double buffer

    const int tid = threadIdx.x;
    const int b0 = blockIdx.x * G;
    const int dq = tid & 3;

    // ---- per-thread uv slice in registers (task- and g-invariant) ----
    // n-task threads (tid<192): row 9+t (= v[t]); e-task threads (192..227): row e (= u[e])
    int urow;
    if (tid < 192) urow = 9 + (tid >> 6);
    else           urow = (tid - 192) >> 2;
    if (urow > 11) urow = 0;              // tid 240..255 would index OOB; they never use it
    float4 uvreg[8];
    #pragma unroll
    for (int k = 0; k < 8; ++k)
        uvreg[k] = *(const float4*)(uv + urow * DIM + 4 * (dq + 4 * k));

    // ---- prefetch all G rows' masks ----
    if (tid < 96) {
        int t = tid >> 5, node = tid & 31;
        #pragma unroll
        for (int g = 0; g < G; ++g)
            mvL[g * 96 + tid] = maskg[(size_t)t * NB * NNODES + (size_t)(b0 + g) * NNODES + node];
    }

    // ---- initial stage: row b0 -> buffer 0 (swizzled) ----
    {
        const float4* src = (const float4*)(hg + (size_t)b0 * (NNODES * DIM));
        float4 p0[4];
        #pragma unroll
        for (int k = 0; k < 4; ++k) p0[k] = src[tid + k * 256];
        #pragma unroll
        for (int k = 0; k < 4; ++k) {
            int idx = tid + k * 256;
            ((float4*)hL)[swz_slot(idx >> 5, idx & 31)] = p0[k];
        }
    }
    __syncthreads();

    float4 pre[4];      // register prefetch of next row (lives across 2 barriers)

    for (int g = 0; g < G; ++g) {
        const float* hb = hL + (g & 1) * (NNODES * DIM);

        // ---- issue global loads for row g+1 (consumed in combine phase) ----
        if (g + 1 < G) {
            const float4* src = (const float4*)(hg + (size_t)(b0 + g + 1) * (NNODES * DIM));
            #pragma unroll
            for (int k = 0; k < 4; ++k) pre[k] = src[tid + k * 256];
        }

        // ---- phase 1: 105 dots as (t, n-pair, d-quarter) tasks, uv from registers ----
        if (tid < 228) {
            const float4* hb4 = (const float4*)hb;
            if (tid < 192) {
                int task4 = tid >> 2;
                int t  = task4 >> 4;
                int n0 = (task4 & 15) * 2;
                float a0 = 0.f, a1 = 0.f;
                #pragma unroll
                for (int k = 0; k < 8; ++k) {
                    int c = dq + 4 * k;
                    float4 x0 = hb4[swz_slot(n0,     c)];
                    float4 x1 = hb4[swz_slot(n0 + 1, c)];
                    float4 u  = uvreg[k];
                    a0 += x0.x*u.x + x0.y*u.y + x0.z*u.z + x0.w*u.w;
                    a1 += x1.x*u.x + x1.y*u.y + x1.z*u.z + x1.w*u.w;
                }
                a0 += __shfl_xor(a0, 1, 64); a0 += __shfl_xor(a0, 2, 64);
                a1 += __shfl_xor(a1, 1, 64); a1 += __shfl_xor(a1, 2, 64);
                if (dq == 0) { sNb[t * 32 + n0] = a0; sNb[t * 32 + n0 + 1] = a1; }
            } else {
                int e = (tid - 192) >> 2;   // 0..8, groups of 4 lanes (4-aligned, shfl-safe)
                float a = 0.f;
                #pragma unroll
                for (int k = 0; k < 8; ++k) {
                    int c = dq + 4 * k;
                    float4 x = hb4[c];      // row 0: swizzle is identity
                    float4 u = uvreg[k];
                    a += x.x*u.x + x.y*u.y + x.z*u.z + x.w*u.w;
                }
                a += __shfl_xor(a, 1, 64); a += __shfl_xor(a, 2, 64);
                if (dq == 0) sTop[e] = a;
            }
        }
        lds_barrier();

        // ---- phase 2: masked softmax (ally and opp separate) -> weights in-place in sNb ----
        int wv = tid >> 6;
        if (wv == 0) {
            // ally: (j,n), 45 lanes; i collapsed (3 exps/lane)
            int lane = tid;
            bool act = lane < 45;
            int j = act ? lane / 15 : 0;
            int n = act ? lane % 15 : 0;
            int mk = 1; float sv = 0.f;
            if (act) {
                mk = mvL[g * 96 + j * 32 + 1 + n];
                sv = sNb[j * 32 + 1 + n];
            }
            float e0 = sTop[0 + j] + sv;
            float e1 = sTop[3 + j] + sv;
            float e2 = sTop[6 + j] + sv;
            bool live = act && (mk == 0);
            float lm = live ? fmaxf(e0, fmaxf(e1, e2)) : -__builtin_inff();
            #pragma unroll
            for (int off = 32; off; off >>= 1) lm = fmaxf(lm, __shfl_xor(lm, off, 64));
            float es = live ? (expf(e0 - lm) + expf(e1 - lm) + expf(e2 - lm)) : 0.f;
            float Z = es;
            #pragma unroll
            for (int off = 32; off; off >>= 1) Z += __shfl_xor(Z, off, 64);
            float w = (live && Z > 0.f) ? es / Z : 0.f;
            if (act) sNb[j * 32 + 1 + n] = w;
        } else if (wv == 1) {
            // opp: (j,n), 48 lanes
            int lane = tid - 64;
            bool act = lane < 48;
            int j = act ? (lane >> 4) : 0;
            int n = act ? (lane & 15) : 0;
            int mk = 1; float sv = 0.f;
            if (act) {
                mk = mvL[g * 96 + j * 32 + 16 + n];
                sv = sNb[j * 32 + 16 + n];
            }
            float e0 = sTop[0 + j] + sv;
            float e1 = sTop[3 + j] + sv;
            float e2 = sTop[6 + j] + sv;
            bool live = act && (mk == 0);
            float lm = live ? fmaxf(e0, fmaxf(e1, e2)) : -__builtin_inff();
            #pragma unroll
            for (int off = 32; off; off >>= 1) lm = fmaxf(lm, __shfl_xor(lm, off, 64));
            float es = live ? (expf(e0 - lm) + expf(e1 - lm) + expf(e2 - lm)) : 0.f;
            float Z = es;
            #pragma unroll
            for (int off = 32; off; off >>= 1) Z += __shfl_xor(Z, off, 64);
            float w = (live && Z > 0.f) ? es / Z : 0.f;
            if (act) sNb[j * 32 + 16 + n] = w;
        } else if (wv == 2) {
            int lane = tid - 128;
            if (lane < 3)
                sNb[lane * 32 + 0] = mvL[g * 96 + lane * 32 + 0] ? 1.f : 0.f; // self: True -> included
        }
        lds_barrier();

        // ---- combine: gAll[g][t][d] = sum_n w[t][n] * h[n][d] (swizzle-aware reads) ----
        if (tid < 128) {
            int d = tid;
            int chi = d >> 2, clo = d & 3;
            float a0 = 0.f, a1 = 0.f, a2 = 0.f;
            #pragma unroll
            for (int n = 0; n < NNODES; ++n) {
                float hv = hb[n * DIM + ((chi ^ (n & 7)) << 2) + clo];
                a0 += sNb[n] * hv;
                a1 += sNb[NNODES + n] * hv;
                a2 += sNb[2 * NNODES + n] * hv;
            }
            float* gp = &gAll[g * TT * DIM];
            gp[d] = a0; gp[DIM + d] = a1; gp[2 * DIM + d] = a2;
        }

        // ---- land the prefetched row into the other buffer (vmcnt wait is implicit) ----
        if (g + 1 < G) {
            float* nb = hL + ((g + 1) & 1) * (NNODES * DIM);
            #pragma unroll
            for (int k = 0; k < 4; ++k) {
                int idx = tid + k * 256;
                ((float4*)nb)[swz_slot(idx >> 5, idx & 31)] = pre[k];
            }
        }
        lds_barrier();
    }

    // ---- epilogue: out[b0+g][h] = sum_t sum_d gAll[g][t][d] * W[t][d][h] ----
    // 256 threads = 32 h-quads x 8 d-groups of 16; W streamed once per block (float4).
    {
        int hq  = tid & 31;          // h0 = 4*hq
        int dq8 = tid >> 5;          // 0..7
        float4 acc[G];
        #pragma unroll
        for (int g = 0; g < G; ++g) acc[g] = make_float4(0.f, 0.f, 0.f, 0.f);
        #pragma unroll
        for (int t = 0; t < TT; ++t) {
            const float* wbase = Wg + ((size_t)t * DIM + dq8 * 16) * HID + 4 * hq;
            const float* gbase = &gAll[t * DIM + dq8 * 16];
            #pragma unroll 4
            for (int dd = 0; dd < 16; ++dd) {
                float4 wq = *(const float4*)(wbase + dd * HID);
                #pragma unroll
                for (int g = 0; g < G; ++g) {
                    float gv = gbase[g * TT * DIM + dd];   // near-uniform -> LDS broadcast
                    acc[g].x += gv * wq.x;
                    acc[g].y += gv * wq.y;
                    acc[g].z += gv * wq.z;
                    acc[g].w += gv * wq.w;
                }
            }
        }
        // partials into dead hL buffer 0 (8 d-groups x G x 128 = 16 KB)
        float* pL = hL;
        #pragma unroll
        for (int g = 0; g < G; ++g)
            *(float4*)&pL[(dq8 * G + g) * DIM + 4 * hq] = acc[g];
    }
    __syncthreads();

    // ---- final: reduce 8 partials, ELU, fp32 store ----
    #pragma unroll
    for (int r = 0; r < 2; ++r) {
        int idx = tid + r * 256;        // 0..511 -> (g, h)
        int g = idx >> 7, h = idx & 127;
        float s = 0.f;
        #pragma unroll
        for (int p = 0; p < 8; ++p) s += hL[p * 512 + idx];
        float rr = (s > 0.f) ? s : expm1f(s);
        outg[(size_t)(b0 + g) * DIM + h] = rr;
    }
}

extern "C" void kernel_launch(void* const* d_in, const int* in_sizes, int n_in,
                              void* d_out, int out_size, void* d_ws, size_t ws_size,
                              hipStream_t stream) {
    const float* hg    = (const float*)d_in[0];    // h (B,32,128) fp32
    const int*   maskg = (const int*)d_in[1];      // ALL_TYPE_MASK (3,B,32) 4-byte words
    // d_in[2]=num_ally, d_in[3]=num_opp, d_in[4]=self_type (fixed)
    const float* Wg    = (const float*)d_in[5];    // W (3,128,128) fp32
    const float* ag    = (const float*)d_in[6];    // a (3,256,1) fp32
    float* uv = (float*)d_ws;                      // 12*128 fp32 scratch (validated)
    float* outg = (float*)d_out;                   // fp32 output

    gat_prep<<<12, 128, 0, stream>>>(Wg, ag, uv);
    gat_main<<<NBLK, 256, 0, stream>>>(hg, maskg, Wg, uv, outg);
}

// Round 3
// 270.527 us; speedup vs baseline: 1.0687x; 1.0687x over previous
//
#include <hip/hip_runtime.h>
#include <math.h>

#define NB 8192
#define G 4                 // batch rows per block
#define NBLK (NB / G)
#define NNODES 32
#define TT 3
#define DIM 128
#define HID 128

// Kernel 1: uv[e][d], e<9: u[i=e/3][j=e%3][d] = W[i] row d . a_top[j]
//           e=9+t:    v[t][d]                 = W[t] row d . a_bot[t]
// Identical for all batch rows -> compute ONCE into d_ws (ws validated earlier).
__global__ __launch_bounds__(128) void gat_prep(
    const float* __restrict__ Wg,   // (3,128,128) fp32
    const float* __restrict__ ag,   // (3,256,1)   fp32
    float* __restrict__ uv)         // (12,128)    fp32
{
    int e = blockIdx.x, d = threadIdx.x;
    int wi, aoff;
    if (e < 9) { wi = e / 3; aoff = (e % 3) * 2 * HID; }        // a_top[j]
    else       { wi = e - 9; aoff = wi * 2 * HID + HID; }       // a_bot[t]
    const float* wrow = Wg + wi * DIM * HID + d * HID;
    const float* arow = ag + aoff;
    float acc = 0.f;
    #pragma unroll 16
    for (int h = 0; h < HID; ++h) acc += wrow[h] * arow[h];
    uv[e * DIM + d] = acc;
}

// Chunk (n, c) of a 32x128 fp32 row-tile lives at float4-slot n*32 + (c ^ (n&7)).
// XOR is an involution: global_load_lds writes LINEAR dest slots while each lane
// reads the pre-swizzled global source chunk; LDS readers apply the same XOR.
__device__ __forceinline__ int swz_slot(int n, int c) { return n * 32 + (c ^ (n & 7)); }

// LDS-only barrier: drains lgkmcnt but NOT vmcnt, so in-flight global_load_lds
// DMA (tracked by vmcnt) keeps running across the barrier.
__device__ __forceinline__ void lds_barrier() {
    asm volatile("s_waitcnt lgkmcnt(0)" ::: "memory");
    __builtin_amdgcn_s_barrier();
}

// Stage one 16 KB h-row into LDS via direct global->LDS DMA (no VGPR staging).
// Linear LDS dest (wave-uniform base + lane*16), per-lane pre-swizzled source.
__device__ __forceinline__ void stage_row(const float* __restrict__ hrow,
                                          float* lbuf, int tid) {
    const int wv = tid >> 6, lane = tid & 63;
    #pragma unroll
    for (int k = 0; k < 4; ++k) {
        int s = wv * 256 + k * 64 + lane;          // linear dest float4-slot
        int n = s >> 5, c = s & 31;
        const float4* g = (const float4*)hrow + (n * 32 + (c ^ (n & 7)));
        float4* l = (float4*)lbuf + (wv * 256 + k * 64);   // wave-uniform base
        __builtin_amdgcn_global_load_lds(
            (const __attribute__((address_space(1))) void*)g,
            (__attribute__((address_space(3))) void*)l, 16, 0, 0);
    }
}

__global__ __launch_bounds__(256, 4) void gat_main(
    const float* __restrict__ hg,     // (B,32,128) fp32
    const int* __restrict__ maskg,    // (3,B,32) 4-byte bool words
    const float* __restrict__ Wg,     // (3,128,128) fp32
    const float* __restrict__ uv,     // (12,128) fp32 (from d_ws)
    float* __restrict__ outg)         // (B,128) fp32
{
    __shared__ __align__(16) float hL[2 * NNODES * DIM]; // 32 KB double-buffered h row (swizzled)
    __shared__ float gAll[G * TT * DIM];                 // 6 KB weighted features
    __shared__ float sTop[16];                           // [3i+j]
    __shared__ float sNb[TT * NNODES];                   // scores, overwritten in-place by weights
    __shared__ int   mvL[G * 96];                        // 1.5 KB prefetched masks
    // total 40,896 B -> 4 blocks/CU with the double buffer

    const int tid = threadIdx.x;
    const int b0 = blockIdx.x * G;
    const int dq = tid & 3;

    // ---- per-thread uv slice in registers (task- and g-invariant) ----
    // n-task threads (tid<192): row 9+t (= v[t]); e-task threads (192..227): row e (= u[e])
    int urow;
    if (tid < 192) urow = 9 + (tid >> 6);
    else           urow = (tid - 192) >> 2;
    if (urow > 11) urow = 0;              // tid 240..255 would index OOB; they never use it
    float4 uvreg[8];
    #pragma unroll
    for (int k = 0; k < 8; ++k)
        uvreg[k] = *(const float4*)(uv + urow * DIM + 4 * (dq + 4 * k));

    // ---- prefetch all G rows' masks ----
    if (tid < 96) {
        int t = tid >> 5, node = tid & 31;
        #pragma unroll
        for (int g = 0; g < G; ++g)
            mvL[g * 96 + tid] = maskg[(size_t)t * NB * NNODES + (size_t)(b0 + g) * NNODES + node];
    }

    // ---- initial stage: row b0 -> buffer 0 (DMA, swizzled source) ----
    stage_row(hg + (size_t)b0 * (NNODES * DIM), hL, tid);
    __syncthreads();    // drains vmcnt(0)+lgkmcnt(0): buf0, mvL, uvreg all ready

    for (int g = 0; g < G; ++g) {
        const float* hb = hL + (g & 1) * (NNODES * DIM);

        // ---- issue DMA for row g+1 into the other buffer (waited at end of iter) ----
        if (g + 1 < G)
            stage_row(hg + (size_t)(b0 + g + 1) * (NNODES * DIM),
                      hL + ((g + 1) & 1) * (NNODES * DIM), tid);

        // ---- phase 1: 105 dots as (t, n-pair, d-quarter) tasks, uv from registers ----
        if (tid < 228) {
            const float4* hb4 = (const float4*)hb;
            if (tid < 192) {
                int task4 = tid >> 2;
                int t  = task4 >> 4;
                int n0 = (task4 & 15) * 2;
                float a0 = 0.f, a1 = 0.f;
                #pragma unroll
                for (int k = 0; k < 8; ++k) {
                    int c = dq + 4 * k;
                    float4 x0 = hb4[swz_slot(n0,     c)];
                    float4 x1 = hb4[swz_slot(n0 + 1, c)];
                    float4 u  = uvreg[k];
                    a0 += x0.x*u.x + x0.y*u.y + x0.z*u.z + x0.w*u.w;
                    a1 += x1.x*u.x + x1.y*u.y + x1.z*u.z + x1.w*u.w;
                }
                a0 += __shfl_xor(a0, 1, 64); a0 += __shfl_xor(a0, 2, 64);
                a1 += __shfl_xor(a1, 1, 64); a1 += __shfl_xor(a1, 2, 64);
                if (dq == 0) { sNb[t * 32 + n0] = a0; sNb[t * 32 + n0 + 1] = a1; }
            } else {
                int e = (tid - 192) >> 2;   // 0..8, groups of 4 lanes (4-aligned, shfl-safe)
                float a = 0.f;
                #pragma unroll
                for (int k = 0; k < 8; ++k) {
                    int c = dq + 4 * k;
                    float4 x = hb4[c];      // row 0: swizzle is identity
                    float4 u = uvreg[k];
                    a += x.x*u.x + x.y*u.y + x.z*u.z + x.w*u.w;
                }
                a += __shfl_xor(a, 1, 64); a += __shfl_xor(a, 2, 64);
                if (dq == 0) sTop[e] = a;
            }
        }
        lds_barrier();

        // ---- phase 2: masked softmax (ally and opp separate) -> weights in-place in sNb ----
        int wv = tid >> 6;
        if (wv == 0) {
            // ally: (j,n), 45 lanes; i collapsed (3 exps/lane)
            int lane = tid;
            bool act = lane < 45;
            int j = act ? lane / 15 : 0;
            int n = act ? lane % 15 : 0;
            int mk = 1; float sv = 0.f;
            if (act) {
                mk = mvL[g * 96 + j * 32 + 1 + n];
                sv = sNb[j * 32 + 1 + n];
            }
            float e0 = sTop[0 + j] + sv;
            float e1 = sTop[3 + j] + sv;
            float e2 = sTop[6 + j] + sv;
            bool live = act && (mk == 0);
            float lm = live ? fmaxf(e0, fmaxf(e1, e2)) : -__builtin_inff();
            #pragma unroll
            for (int off = 32; off; off >>= 1) lm = fmaxf(lm, __shfl_xor(lm, off, 64));
            float es = live ? (expf(e0 - lm) + expf(e1 - lm) + expf(e2 - lm)) : 0.f;
            float Z = es;
            #pragma unroll
            for (int off = 32; off; off >>= 1) Z += __shfl_xor(Z, off, 64);
            float w = (live && Z > 0.f) ? es / Z : 0.f;
            if (act) sNb[j * 32 + 1 + n] = w;
        } else if (wv == 1) {
            // opp: (j,n), 48 lanes
            int lane = tid - 64;
            bool act = lane < 48;
            int j = act ? (lane >> 4) : 0;
            int n = act ? (lane & 15) : 0;
            int mk = 1; float sv = 0.f;
            if (act) {
                mk = mvL[g * 96 + j * 32 + 16 + n];
                sv = sNb[j * 32 + 16 + n];
            }
            float e0 = sTop[0 + j] + sv;
            float e1 = sTop[3 + j] + sv;
            float e2 = sTop[6 + j] + sv;
            bool live = act && (mk == 0);
            float lm = live ? fmaxf(e0, fmaxf(e1, e2)) : -__builtin_inff();
            #pragma unroll
            for (int off = 32; off; off >>= 1) lm = fmaxf(lm, __shfl_xor(lm, off, 64));
            float es = live ? (expf(e0 - lm) + expf(e1 - lm) + expf(e2 - lm)) : 0.f;
            float Z = es;
            #pragma unroll
            for (int off = 32; off; off >>= 1) Z += __shfl_xor(Z, off, 64);
            float w = (live && Z > 0.f) ? es / Z : 0.f;
            if (act) sNb[j * 32 + 16 + n] = w;
        } else if (wv == 2) {
            int lane = tid - 128;
            if (lane < 3)
                sNb[lane * 32 + 0] = mvL[g * 96 + lane * 32 + 0] ? 1.f : 0.f; // self: True -> included
        }
        lds_barrier();

        // ---- combine: gAll[g][t][d] = sum_n w[t][n] * h[n][d] (swizzle-aware reads) ----
        if (tid < 128) {
            int d = tid;
            int chi = d >> 2, clo = d & 3;
            float a0 = 0.f, a1 = 0.f, a2 = 0.f;
            #pragma unroll
            for (int n = 0; n < NNODES; ++n) {
                float hv = hb[n * DIM + ((chi ^ (n & 7)) << 2) + clo];
                a0 += sNb[n] * hv;
                a1 += sNb[NNODES + n] * hv;
                a2 += sNb[2 * NNODES + n] * hv;
            }
            float* gp = &gAll[g * TT * DIM];
            gp[d] = a0; gp[DIM + d] = a1; gp[2 * DIM + d] = a2;
        }

        // ---- end of iter: wait for prefetch DMA + all LDS ops, then barrier ----
        asm volatile("s_waitcnt vmcnt(0) lgkmcnt(0)" ::: "memory");
        __builtin_amdgcn_s_barrier();
    }

    // ---- epilogue: out[b0+g][h] = sum_t sum_d gAll[g][t][d] * W[t][d][h] ----
    // 256 threads = 32 h-quads x 8 d-groups of 16; W streamed once per block (float4).
    {
        int hq  = tid & 31;          // h0 = 4*hq
        int dq8 = tid >> 5;          // 0..7
        float4 acc[G];
        #pragma unroll
        for (int g = 0; g < G; ++g) acc[g] = make_float4(0.f, 0.f, 0.f, 0.f);
        #pragma unroll
        for (int t = 0; t < TT; ++t) {
            const float* wbase = Wg + ((size_t)t * DIM + dq8 * 16) * HID + 4 * hq;
            const float* gbase = &gAll[t * DIM + dq8 * 16];
            #pragma unroll 4
            for (int dd = 0; dd < 16; ++dd) {
                float4 wq = *(const float4*)(wbase + dd * HID);
                #pragma unroll
                for (int g = 0; g < G; ++g) {
                    float gv = gbase[g * TT * DIM + dd];   // near-uniform -> LDS broadcast
                    acc[g].x += gv * wq.x;
                    acc[g].y += gv * wq.y;
                    acc[g].z += gv * wq.z;
                    acc[g].w += gv * wq.w;
                }
            }
        }
        // partials into dead hL buffer 0 (8 d-groups x G x 128 = 16 KB)
        float* pL = hL;
        #pragma unroll
        for (int g = 0; g < G; ++g)
            *(float4*)&pL[(dq8 * G + g) * DIM + 4 * hq] = acc[g];
    }
    __syncthreads();

    // ---- final: reduce 8 partials, ELU, fp32 store ----
    #pragma unroll
    for (int r = 0; r < 2; ++r) {
        int idx = tid + r * 256;        // 0..511 -> (g, h)
        int g = idx >> 7, h = idx & 127;
        float s = 0.f;
        #pragma unroll
        for (int p = 0; p < 8; ++p) s += hL[p * 512 + idx];
        float rr = (s > 0.f) ? s : expm1f(s);
        outg[(size_t)(b0 + g) * DIM + h] = rr;
    }
}

extern "C" void kernel_launch(void* const* d_in, const int* in_sizes, int n_in,
                              void* d_out, int out_size, void* d_ws, size_t ws_size,
                              hipStream_t stream) {
    const float* hg    = (const float*)d_in[0];    // h (B,32,128) fp32
    const int*   maskg = (const int*)d_in[1];      // ALL_TYPE_MASK (3,B,32) 4-byte words
    // d_in[2]=num_ally, d_in[3]=num_opp, d_in[4]=self_type (fixed)
    const float* Wg    = (const float*)d_in[5];    // W (3,128,128) fp32
    const float* ag    = (const float*)d_in[6];    // a (3,256,1) fp32
    float* uv = (float*)d_ws;                      // 12*128 fp32 scratch (validated)
    float* outg = (float*)d_out;                   // fp32 output

    gat_prep<<<12, 128, 0, stream>>>(Wg, ag, uv);
    gat_main<<<NBLK, 256, 0, stream>>>(hg, maskg, Wg, uv, outg);
}

// Round 4
// 227.222 us; speedup vs baseline: 1.2724x; 1.1906x over previous
//
#include <hip/hip_runtime.h>
#include <math.h>

#define NB 8192
#define G 4                 // batch rows per block
#define NBLK (NB / G)
#define NNODES 32
#define TT 3
#define DIM 128
#define HID 128
#define USTR 132            // uvL padded stride (floats): 16B-aligned rows, bank rotation 4/row

// Kernel 1: uv[e][d], e<9: u[i=e/3][j=e%3][d] = W[i] row d . a_top[j]
//           e=9+t:    v[t][d]                 = W[t] row d . a_bot[t]
// Identical for all batch rows -> compute ONCE into d_ws (ws validated earlier).
__global__ __launch_bounds__(128) void gat_prep(
    const float* __restrict__ Wg,   // (3,128,128) fp32
    const float* __restrict__ ag,   // (3,256,1)   fp32
    float* __restrict__ uv)         // (12,128)    fp32
{
    int e = blockIdx.x, d = threadIdx.x;
    int wi, aoff;
    if (e < 9) { wi = e / 3; aoff = (e % 3) * 2 * HID; }        // a_top[j]
    else       { wi = e - 9; aoff = wi * 2 * HID + HID; }       // a_bot[t]
    const float* wrow = Wg + wi * DIM * HID + d * HID;
    const float* arow = ag + aoff;
    float acc = 0.f;
    #pragma unroll 16
    for (int h = 0; h < HID; ++h) acc += wrow[h] * arow[h];
    uv[e * DIM + d] = acc;
}

// Chunk (n, c) of a 32x128 fp32 row-tile lives at float4-slot n*32 + (c ^ (n&7)).
// XOR is an involution: global_load_lds writes LINEAR dest slots while each lane
// reads the pre-swizzled global source chunk; LDS readers apply the same XOR.
__device__ __forceinline__ int swz_slot(int n, int c) { return n * 32 + (c ^ (n & 7)); }

// LDS-only barrier: drains lgkmcnt but NOT vmcnt, so in-flight global_load_lds
// DMA (tracked by vmcnt) keeps running across the barrier.
__device__ __forceinline__ void lds_barrier() {
    asm volatile("s_waitcnt lgkmcnt(0)" ::: "memory");
    __builtin_amdgcn_s_barrier();
}

// Stage one 16 KB h-row into LDS via direct global->LDS DMA (no VGPR staging).
// Linear LDS dest (wave-uniform base + lane*16), per-lane pre-swizzled source.
__device__ __forceinline__ void stage_row(const float* __restrict__ hrow,
                                          float* lbuf, int tid) {
    const int wv = tid >> 6, lane = tid & 63;
    #pragma unroll
    for (int k = 0; k < 4; ++k) {
        int s = wv * 256 + k * 64 + lane;          // linear dest float4-slot
        int n = s >> 5, c = s & 31;
        const float4* g = (const float4*)hrow + (n * 32 + (c ^ (n & 7)));
        float4* l = (float4*)lbuf + (wv * 256 + k * 64);   // wave-uniform base
        __builtin_amdgcn_global_load_lds(
            (const __attribute__((address_space(1))) void*)g,
            (__attribute__((address_space(3))) void*)l, 16, 0, 0);
    }
}

__global__ __launch_bounds__(256, 4) void gat_main(
    const float* __restrict__ hg,     // (B,32,128) fp32
    const int* __restrict__ maskg,    // (3,B,32) 4-byte bool words
    const float* __restrict__ Wg,     // (3,128,128) fp32
    const float* __restrict__ uv,     // (12,128) fp32 (from d_ws)
    float* __restrict__ outg)         // (B,128) fp32
{
    __shared__ __align__(16) float hL[2 * NNODES * DIM];  // 32 KB dbuf h row (swizzled); reused post-loop
    __shared__ __align__(16) float uvL[12 * USTR];        // 6,336 B
    __shared__ float sTop[16];                            // [3i+j]
    __shared__ float sNb[TT * NNODES];                    // scores, overwritten in-place by weights
    __shared__ unsigned char mvB[G * 96];                 // 384 B masks as bytes
    // total 39,936 B -> 4 blocks/CU

    const int tid = threadIdx.x;
    const int b0 = blockIdx.x * G;
    const int dq = tid & 3;

    // ---- stage uv into LDS (1536 elems, 6/thread) ----
    #pragma unroll
    for (int k = 0; k < 6; ++k) {
        int i = tid + k * 256;
        uvL[(i >> 7) * USTR + (i & 127)] = uv[i];
    }
    // ---- prefetch all G rows' masks (as bytes) ----
    if (tid < 96) {
        int t = tid >> 5, node = tid & 31;
        #pragma unroll
        for (int g = 0; g < G; ++g)
            mvB[g * 96 + tid] = (unsigned char)(
                maskg[(size_t)t * NB * NNODES + (size_t)(b0 + g) * NNODES + node] ? 1 : 0);
    }

    // ---- initial stage: row b0 -> buffer 0 (DMA, swizzled source) ----
    stage_row(hg + (size_t)b0 * (NNODES * DIM), hL, tid);
    __syncthreads();    // drains vmcnt(0)+lgkmcnt(0): buf0, uvL, mvB all ready

    float gr[G][TT];    // combine accumulators, statically indexed (g-loop fully unrolled)

    #pragma unroll
    for (int g = 0; g < G; ++g) {
        const float* hb = hL + (g & 1) * (NNODES * DIM);

        // ---- issue DMA for row g+1 into the other buffer (waited at end of iter) ----
        if (g + 1 < G)
            stage_row(hg + (size_t)(b0 + g + 1) * (NNODES * DIM),
                      hL + ((g + 1) & 1) * (NNODES * DIM), tid);

        // ---- phase 1: 105 dots as (t, n-pair, d-quarter) tasks, u/v from uvL ----
        if (tid < 228) {
            const float4* hb4 = (const float4*)hb;
            if (tid < 192) {
                int task4 = tid >> 2;
                int t  = task4 >> 4;                 // == tid>>6, wave-uniform row
                int n0 = (task4 & 15) * 2;
                const float4* up = (const float4*)&uvL[(9 + t) * USTR];
                float a0 = 0.f, a1 = 0.f;
                #pragma unroll
                for (int k = 0; k < 8; ++k) {
                    int c = dq + 4 * k;
                    float4 x0 = hb4[swz_slot(n0,     c)];
                    float4 x1 = hb4[swz_slot(n0 + 1, c)];
                    float4 u  = up[c];
                    a0 += x0.x*u.x + x0.y*u.y + x0.z*u.z + x0.w*u.w;
                    a1 += x1.x*u.x + x1.y*u.y + x1.z*u.z + x1.w*u.w;
                }
                a0 += __shfl_xor(a0, 1, 64); a0 += __shfl_xor(a0, 2, 64);
                a1 += __shfl_xor(a1, 1, 64); a1 += __shfl_xor(a1, 2, 64);
                if (dq == 0) { sNb[t * 32 + n0] = a0; sNb[t * 32 + n0 + 1] = a1; }
            } else {
                int e = (tid - 192) >> 2;   // 0..8, groups of 4 lanes (4-aligned, shfl-safe)
                const float4* up = (const float4*)&uvL[e * USTR];
                float a = 0.f;
                #pragma unroll
                for (int k = 0; k < 8; ++k) {
                    int c = dq + 4 * k;
                    float4 x = hb4[c];      // row 0: swizzle is identity
                    float4 u = up[c];
                    a += x.x*u.x + x.y*u.y + x.z*u.z + x.w*u.w;
                }
                a += __shfl_xor(a, 1, 64); a += __shfl_xor(a, 2, 64);
                if (dq == 0) sTop[e] = a;
            }
        }
        lds_barrier();

        // ---- phase 2: masked softmax (ally and opp separate) -> weights in-place in sNb ----
        int wv = tid >> 6;
        if (wv == 0) {
            // ally: (j,n), 45 lanes; i collapsed (3 exps/lane)
            int lane = tid;
            bool act = lane < 45;
            int j = act ? lane / 15 : 0;
            int n = act ? lane % 15 : 0;
            int mk = 1; float sv = 0.f;
            if (act) {
                mk = mvB[g * 96 + j * 32 + 1 + n];
                sv = sNb[j * 32 + 1 + n];
            }
            float e0 = sTop[0 + j] + sv;
            float e1 = sTop[3 + j] + sv;
            float e2 = sTop[6 + j] + sv;
            bool live = act && (mk == 0);
            float lm = live ? fmaxf(e0, fmaxf(e1, e2)) : -__builtin_inff();
            #pragma unroll
            for (int off = 32; off; off >>= 1) lm = fmaxf(lm, __shfl_xor(lm, off, 64));
            float es = live ? (expf(e0 - lm) + expf(e1 - lm) + expf(e2 - lm)) : 0.f;
            float Z = es;
            #pragma unroll
            for (int off = 32; off; off >>= 1) Z += __shfl_xor(Z, off, 64);
            float w = (live && Z > 0.f) ? es / Z : 0.f;
            if (act) sNb[j * 32 + 1 + n] = w;
        } else if (wv == 1) {
            // opp: (j,n), 48 lanes
            int lane = tid - 64;
            bool act = lane < 48;
            int j = act ? (lane >> 4) : 0;
            int n = act ? (lane & 15) : 0;
            int mk = 1; float sv = 0.f;
            if (act) {
                mk = mvB[g * 96 + j * 32 + 16 + n];
                sv = sNb[j * 32 + 16 + n];
            }
            float e0 = sTop[0 + j] + sv;
            float e1 = sTop[3 + j] + sv;
            float e2 = sTop[6 + j] + sv;
            bool live = act && (mk == 0);
            float lm = live ? fmaxf(e0, fmaxf(e1, e2)) : -__builtin_inff();
            #pragma unroll
            for (int off = 32; off; off >>= 1) lm = fmaxf(lm, __shfl_xor(lm, off, 64));
            float es = live ? (expf(e0 - lm) + expf(e1 - lm) + expf(e2 - lm)) : 0.f;
            float Z = es;
            #pragma unroll
            for (int off = 32; off; off >>= 1) Z += __shfl_xor(Z, off, 64);
            float w = (live && Z > 0.f) ? es / Z : 0.f;
            if (act) sNb[j * 32 + 16 + n] = w;
        } else if (wv == 2) {
            int lane = tid - 128;
            if (lane < 3)
                sNb[lane * 32 + 0] = mvB[g * 96 + lane * 32 + 0] ? 1.f : 0.f; // self: True -> included
        }
        lds_barrier();

        // ---- combine into registers: gr[g][t] for d = tid (swizzle-aware reads) ----
        if (tid < 128) {
            int d = tid;
            int chi = d >> 2, clo = d & 3;
            float a0 = 0.f, a1 = 0.f, a2 = 0.f;
            #pragma unroll
            for (int n = 0; n < NNODES; ++n) {
                float hv = hb[n * DIM + ((chi ^ (n & 7)) << 2) + clo];
                a0 += sNb[n] * hv;
                a1 += sNb[NNODES + n] * hv;
                a2 += sNb[2 * NNODES + n] * hv;
            }
            gr[g][0] = a0; gr[g][1] = a1; gr[g][2] = a2;
        }

        // ---- end of iter: wait for prefetch DMA + all LDS ops, then barrier ----
        asm volatile("s_waitcnt vmcnt(0) lgkmcnt(0)" ::: "memory");
        __builtin_amdgcn_s_barrier();
    }

    // ---- dump gr into dead hL: gA[g*384 + t*128 + d] (floats 0..1535) ----
    if (tid < 128) {
        #pragma unroll
        for (int g = 0; g < G; ++g) {
            hL[g * 384 + 0 * 128 + tid] = gr[g][0];
            hL[g * 384 + 1 * 128 + tid] = gr[g][1];
            hL[g * 384 + 2 * 128 + tid] = gr[g][2];
        }
    }
    __syncthreads();

    // ---- epilogue: out[b0+g][h] = sum_t sum_d gA[g][t][d] * W[t][d][h] ----
    // 256 threads = 32 h-quads x 8 d-groups of 16; W streamed once per block (float4).
    {
        int hq  = tid & 31;          // h0 = 4*hq
        int dq8 = tid >> 5;          // 0..7
        float4 acc[G];
        #pragma unroll
        for (int g = 0; g < G; ++g) acc[g] = make_float4(0.f, 0.f, 0.f, 0.f);
        #pragma unroll
        for (int t = 0; t < TT; ++t) {
            const float* wbase = Wg + ((size_t)t * DIM + dq8 * 16) * HID + 4 * hq;
            const float* gbase = &hL[t * 128 + dq8 * 16];
            #pragma unroll 4
            for (int dd = 0; dd < 16; ++dd) {
                float4 wq = *(const float4*)(wbase + dd * HID);
                #pragma unroll
                for (int g = 0; g < G; ++g) {
                    float gv = gbase[g * 384 + dd];   // near-uniform -> LDS broadcast
                    acc[g].x += gv * wq.x;
                    acc[g].y += gv * wq.y;
                    acc[g].z += gv * wq.z;
                    acc[g].w += gv * wq.w;
                }
            }
        }
        // partials into hL floats 2048..6143 (8 d-groups x G x 128 = 16 KB)
        float* pL = hL + 2048;
        #pragma unroll
        for (int g = 0; g < G; ++g)
            *(float4*)&pL[(dq8 * G + g) * DIM + 4 * hq] = acc[g];
    }
    __syncthreads();

    // ---- final: reduce 8 partials, ELU, fp32 store ----
    #pragma unroll
    for (int r = 0; r < 2; ++r) {
        int idx = tid + r * 256;        // 0..511 -> (g, h)
        int g = idx >> 7, h = idx & 127;
        const float* pL = hL + 2048;
        float s = 0.f;
        #pragma unroll
        for (int p = 0; p < 8; ++p) s += pL[p * 512 + idx];
        float rr = (s > 0.f) ? s : expm1f(s);
        outg[(size_t)(b0 + g) * DIM + h] = rr;
    }
}

extern "C" void kernel_launch(void* const* d_in, const int* in_sizes, int n_in,
                              void* d_out, int out_size, void* d_ws, size_t ws_size,
                              hipStream_t stream) {
    const float* hg    = (const float*)d_in[0];    // h (B,32,128) fp32
    const int*   maskg = (const int*)d_in[1];      // ALL_TYPE_MASK (3,B,32) 4-byte words
    // d_in[2]=num_ally, d_in[3]=num_opp, d_in[4]=self_type (fixed)
    const float* Wg    = (const float*)d_in[5];    // W (3,128,128) fp32
    const float* ag    = (const float*)d_in[6];    // a (3,256,1) fp32
    float* uv = (float*)d_ws;                      // 12*128 fp32 scratch (validated)
    float* outg = (float*)d_out;                   // fp32 output

    gat_prep<<<12, 128, 0, stream>>>(Wg, ag, uv);
    gat_main<<<NBLK, 256, 0, stream>>>(hg, maskg, Wg, uv, outg);
}